// Round 1
// baseline (496.472 us; speedup 1.0000x reference)
//
#include <hip/hip_runtime.h>
#include <math.h>

#define N_IMG 256
#define DIN   768
#define DH    768
#define DOUT  512
#define M_GAL 100000
#define CAP   2048

typedef __bf16 bf16_t;
typedef __bf16 bf16x8 __attribute__((ext_vector_type(8)));
typedef __bf16 bf16x4 __attribute__((ext_vector_type(4)));
typedef float  f32x4  __attribute__((ext_vector_type(4)));

// ---- workspace layout (float units) ----
#define OFF_H      0                               // 256*768
#define OFF_IMG    (N_IMG*DH)                      // 256*512 pre-norm
#define OFF_IMGN   (OFF_IMG  + N_IMG*DOUT)         // 256*512 f32 normalized
#define OFF_IMGBF  (OFF_IMGN + N_IMG*DOUT)         // 256*512 bf16 (65536 floats)
#define OFF_STATS  (OFF_IMGBF + N_IMG*DOUT/2)      // [0]=sumexp [1]=maxkey [2]=counter
#define OFF_CIDX   (OFF_STATS + 4)
#define OFF_CVAL   (OFF_CIDX + CAP)

#define OUT_GPS  ((size_t)N_IMG * (size_t)M_GAL)
#define OUT_PROB (OUT_GPS + 10)

__device__ inline unsigned fkey(float x) {
  unsigned u = __float_as_uint(x);
  return (u & 0x80000000u) ? ~u : (u | 0x80000000u);
}
__device__ inline float fkey_inv(unsigned k) {
  unsigned u = (k & 0x80000000u) ? (k ^ 0x80000000u) : ~k;
  return __uint_as_float(u);
}

// ---------------- MLP GEMM (f32 VALU, 32x32 tile, 2x2 micro) ----------------
// C[r, c] = relu?(sum_k A[r,k]*B[c,k] + bias[c])   A:[*,KDIM] B:[NCOLS,KDIM]
template<int KDIM, int NCOLS, bool RELU>
__global__ __launch_bounds__(256) void mlp_gemm(const float* __restrict__ A,
    const float* __restrict__ B, const float* __restrict__ bias,
    float* __restrict__ C, unsigned* stats_init) {
  if (stats_init && blockIdx.x == 0 && blockIdx.y == 0 && threadIdx.x == 0) {
    stats_init[0] = 0u; stats_init[1] = 0u; stats_init[2] = 0u;  // sumexp,maxkey,counter
  }
  __shared__ float As[32][34];   // [k][m], pad 34: 2-way max on write, broadcast read
  __shared__ float Bs[32][34];   // [k][n]
  const int t  = threadIdx.x;
  const int rowbase = blockIdx.y * 32;
  const int colbase = blockIdx.x * 32;
  const int sm = t >> 3;          // staging row 0..31
  const int kc = (t & 7) << 2;    // staging k 0,4..28
  const int ty = t >> 4, tx = t & 15;
  float a00 = 0.f, a01 = 0.f, a10 = 0.f, a11 = 0.f;
  for (int kt = 0; kt < KDIM; kt += 32) {
    float4 av = *(const float4*)(A + (size_t)(rowbase + sm) * KDIM + kt + kc);
    float4 bv = *(const float4*)(B + (size_t)(colbase + sm) * KDIM + kt + kc);
    __syncthreads();
    As[kc+0][sm] = av.x; As[kc+1][sm] = av.y; As[kc+2][sm] = av.z; As[kc+3][sm] = av.w;
    Bs[kc+0][sm] = bv.x; Bs[kc+1][sm] = bv.y; Bs[kc+2][sm] = bv.z; Bs[kc+3][sm] = bv.w;
    __syncthreads();
#pragma unroll
    for (int j = 0; j < 32; ++j) {
      float2 a = *(const float2*)(&As[j][2*ty]);
      float2 b = *(const float2*)(&Bs[j][2*tx]);
      a00 = fmaf(a.x, b.x, a00); a01 = fmaf(a.x, b.y, a01);
      a10 = fmaf(a.y, b.x, a10); a11 = fmaf(a.y, b.y, a11);
    }
  }
  const int r0 = rowbase + 2*ty;
  const int c0 = colbase + 2*tx;
  const float bb0 = bias[c0], bb1 = bias[c0+1];
  float v00 = a00 + bb0, v01 = a01 + bb1, v10 = a10 + bb0, v11 = a11 + bb1;
  if (RELU) {
    v00 = fmaxf(v00, 0.f); v01 = fmaxf(v01, 0.f);
    v10 = fmaxf(v10, 0.f); v11 = fmaxf(v11, 0.f);
  }
  C[(size_t)r0*NCOLS + c0]       = v00; C[(size_t)r0*NCOLS + c0 + 1]     = v01;
  C[(size_t)(r0+1)*NCOLS + c0]   = v10; C[(size_t)(r0+1)*NCOLS + c0 + 1] = v11;
}

// ---------------- normalize rows + bf16 cast ----------------
__global__ __launch_bounds__(256) void norm_cast_kernel(const float* __restrict__ img,
    float* __restrict__ img_n, bf16_t* __restrict__ img_bf) {
  const int row = blockIdx.x, t = threadIdx.x;
  const float v0 = img[row*DOUT + t];
  const float v1 = img[row*DOUT + 256 + t];
  float s = v0*v0 + v1*v1;
  for (int o = 32; o > 0; o >>= 1) s += __shfl_down(s, o);
  __shared__ float ws4[4];
  if ((t & 63) == 0) ws4[t >> 6] = s;
  __syncthreads();
  const float tot = ws4[0] + ws4[1] + ws4[2] + ws4[3];
  const float inv = 1.0f / sqrtf(tot);
  const float n0 = v0 * inv, n1 = v1 * inv;
  img_n[row*DOUT + t]        = n0;
  img_n[row*DOUT + 256 + t]  = n1;
  img_bf[row*DOUT + t]       = (bf16_t)n0;
  img_bf[row*DOUT + 256 + t] = (bf16_t)n1;
}

// ---------------- main logits GEMM: bf16 MFMA, 128x128 tile ----------------
// out[n, m] = scale * sum_k img_bf[n,k] * loc[m,k]   (loc f32 -> bf16 in staging)
__global__ __launch_bounds__(256) void logits_kernel(const float* __restrict__ loc,
    const bf16_t* __restrict__ img_bf, const float* __restrict__ ls,
    float* __restrict__ out) {
  __shared__ bf16_t Al[128 * 32];   // [row][k], stride 32 (layout required by global_load_lds)
  __shared__ bf16_t Bl[128 * 40];   // [row][k], stride 40 (pad vs write conflicts)
  const int t = threadIdx.x;
  const int w = t >> 6, l = t & 63;
  const int bx = blockIdx.x;
  // swizzle: same m-tile's two n-tiles are 8 blocks apart -> same XCD, loc read once from HBM
  const int mtile = (bx >> 4) * 8 + (bx & 7);
  const int ntile = (bx >> 3) & 1;
  const int mb = mtile * 128;
  const int nb = ntile * 128;
  const int wn = (w >> 1) * 64;   // wave's image sub-tile
  const int wm = (w & 1) * 64;    // wave's gallery sub-tile
  const int lr = l & 15, lq = l >> 4;
  f32x4 acc[4][4];
#pragma unroll
  for (int i = 0; i < 4; ++i)
#pragma unroll
    for (int j = 0; j < 4; ++j)
      acc[i][j] = (f32x4){0.f, 0.f, 0.f, 0.f};

  const int srow = t >> 3;          // B staging: row within 32-row group
  const int skc  = (t & 7) << 2;    // k offset 0,4..28

  for (int kt = 0; kt < 512; kt += 32) {
    __syncthreads();   // prior iteration's LDS reads complete
    // ---- stage A tile (128x32 bf16 = 8KB) direct to LDS, 16B/lane ----
#pragma unroll
    for (int r = 0; r < 2; ++r) {
      const int chunk = r*256 + w*64 + l;
      const int row = chunk >> 2;
      const int ko  = (chunk & 3) << 3;
      __builtin_amdgcn_global_load_lds(
          (__attribute__((address_space(1))) void*)(img_bf + (size_t)(nb + row)*512 + kt + ko),
          (__attribute__((address_space(3))) void*)(Al + (r*256 + w*64)*8),
          16, 0, 0);
    }
    // ---- stage B tile: f32 float4 load -> bf16 -> LDS ----
#pragma unroll
    for (int i = 0; i < 4; ++i) {
      const int row = i*32 + srow;
      const int gr = mb + row;
      float4 f = make_float4(0.f, 0.f, 0.f, 0.f);
      if (gr < M_GAL) f = *(const float4*)(loc + (size_t)gr*512 + kt + skc);
      bf16x4 bv;
      bv[0] = (bf16_t)f.x; bv[1] = (bf16_t)f.y; bv[2] = (bf16_t)f.z; bv[3] = (bf16_t)f.w;
      *(bf16x4*)(Bl + row*40 + skc) = bv;
    }
    __syncthreads();
    // ---- fragments + MFMA ----
    bf16x8 af[4], bfr[4];
#pragma unroll
    for (int i = 0; i < 4; ++i)
      af[i] = *(const bf16x8*)(Al + (wn + i*16 + lr)*32 + lq*8);
#pragma unroll
    for (int j = 0; j < 4; ++j)
      bfr[j] = *(const bf16x8*)(Bl + (wm + j*16 + lr)*40 + lq*8);
#pragma unroll
    for (int i = 0; i < 4; ++i)
#pragma unroll
      for (int j = 0; j < 4; ++j)
        acc[i][j] = __builtin_amdgcn_mfma_f32_16x16x32_bf16(af[i], bfr[j], acc[i][j], 0, 0, 0);
  }
  // epilogue: D row = image = (lane>>4)*4 + reg, col = gallery = lane&15  [m89-verified]
  const float scale = expf(ls[0]);
#pragma unroll
  for (int i = 0; i < 4; ++i) {
    const int imgr = nb + wn + i*16 + lq*4;
#pragma unroll
    for (int j = 0; j < 4; ++j) {
      const int gal = mb + wm + j*16 + lr;
      if (gal < M_GAL) {
        const size_t base = (size_t)imgr * M_GAL + gal;
#pragma unroll
        for (int r = 0; r < 4; ++r)
          out[base + (size_t)r * M_GAL] = scale * acc[i][j][r];
      }
    }
  }
}

// ---------------- row-0 stats: global max + sum(exp) ----------------
__global__ __launch_bounds__(256) void row0_stats(const float* __restrict__ out,
    float* __restrict__ sumexp, unsigned* __restrict__ maxkey) {
  const int i = blockIdx.x * 256 + threadIdx.x;
  float v = -1e30f, e = 0.f;
  if (i < M_GAL) { v = out[i]; e = expf(v); }
  for (int o = 32; o > 0; o >>= 1) {
    v = fmaxf(v, __shfl_down(v, o));
    e += __shfl_down(e, o);
  }
  __shared__ float wm4[4], ws4[4];
  const int t = threadIdx.x;
  if ((t & 63) == 0) { wm4[t>>6] = v; ws4[t>>6] = e; }
  __syncthreads();
  if (t == 0) {
    const float mv = fmaxf(fmaxf(wm4[0], wm4[1]), fmaxf(wm4[2], wm4[3]));
    const float sv = ws4[0] + ws4[1] + ws4[2] + ws4[3];
    atomicAdd(sumexp, sv);
    atomicMax(maxkey, fkey(mv));
  }
}

// ---------------- collect candidates within 0.8 of max ----------------
__global__ __launch_bounds__(256) void collect_kernel(const float* __restrict__ out,
    const unsigned* __restrict__ maxkey, unsigned* __restrict__ counter,
    int* __restrict__ cidx) {
  const int i = blockIdx.x * 256 + threadIdx.x;
  if (i >= M_GAL) return;
  const float thresh = fkey_inv(*maxkey) - 0.8f;
  if (out[i] > thresh) {
    const unsigned p = atomicAdd(counter, 1u);
    if (p < CAP) cidx[p] = i;
  }
}

// ---------------- exact f32 recompute of candidate logits ----------------
__global__ __launch_bounds__(256) void recompute_kernel(const float* __restrict__ loc,
    const float* __restrict__ img_n, const float* __restrict__ ls,
    const unsigned* __restrict__ counter, const int* __restrict__ cidx,
    float* __restrict__ cval) {
  const int w = threadIdx.x >> 6, l = threadIdx.x & 63;
  const unsigned cnt = *counter;
  const int n = (int)(cnt < CAP ? cnt : CAP);
  const float scale = expf(ls[0]);
  for (int c = blockIdx.x * 4 + w; c < n; c += gridDim.x * 4) {
    const int idx = cidx[c];
    const float* B = loc + (size_t)idx * 512;
    float s = 0.f;
#pragma unroll
    for (int e = 0; e < 8; ++e) s = fmaf(img_n[l + e*64], B[l + e*64], s);
    for (int o = 32; o > 0; o >>= 1) s += __shfl_down(s, o);
    if (l == 0) cval[c] = scale * s;
  }
}

// ---------------- exact top-5 among candidates + outputs ----------------
__global__ __launch_bounds__(256) void finalize_kernel(const unsigned* __restrict__ counter,
    const int* __restrict__ cidx, const float* __restrict__ cval,
    const float* __restrict__ gps, const float* __restrict__ sumexp,
    float* __restrict__ out) {
  __shared__ float v[CAP];
  __shared__ int   id[CAP];
  __shared__ float rv[256];
  __shared__ int   ri[256];
  __shared__ int   rs[256];
  const int t = threadIdx.x;
  const unsigned cnt = *counter;
  const int n = (int)(cnt < CAP ? cnt : CAP);
  for (int i = t; i < CAP; i += 256) {
    v[i]  = (i < n) ? cval[i] : -1e30f;
    id[i] = (i < n) ? cidx[i] : 0x7fffffff;
  }
  const float se = *sumexp;
  __syncthreads();
  for (int k = 0; k < 5; ++k) {
    float bv = -1e30f; int bidx = 0x7fffffff; int bslot = -1;
    for (int i = t; i < CAP; i += 256) {
      const float vi = v[i]; const int ii = id[i];
      if (vi > bv || (vi == bv && ii < bidx)) { bv = vi; bidx = ii; bslot = i; }
    }
    rv[t] = bv; ri[t] = bidx; rs[t] = bslot;
    __syncthreads();
    for (int s = 128; s > 0; s >>= 1) {
      if (t < s) {
        if (rv[t+s] > rv[t] || (rv[t+s] == rv[t] && ri[t+s] < ri[t])) {
          rv[t] = rv[t+s]; ri[t] = ri[t+s]; rs[t] = rs[t+s];
        }
      }
      __syncthreads();
    }
    if (t == 0) {
      const int sl = rs[0]; const int gi = ri[0]; const float lv = rv[0];
      float g0 = 0.f, g1 = 0.f, pr = 0.f;
      if (sl >= 0 && gi != 0x7fffffff) {
        g0 = gps[(size_t)gi*2]; g1 = gps[(size_t)gi*2 + 1];
        pr = expf(lv) / se;
        v[sl] = -1e30f; id[sl] = 0x7fffffff;   // remove winner
      }
      out[OUT_GPS + 2*k]     = g0;
      out[OUT_GPS + 2*k + 1] = g1;
      out[OUT_PROB + k]      = pr;
    }
    __syncthreads();
  }
}

extern "C" void kernel_launch(void* const* d_in, const int* in_sizes, int n_in,
                              void* d_out, int out_size, void* d_ws, size_t ws_size,
                              hipStream_t stream) {
  const float* img_feats = (const float*)d_in[0];
  const float* w1  = (const float*)d_in[1];
  const float* b1  = (const float*)d_in[2];
  const float* w2  = (const float*)d_in[3];
  const float* b2  = (const float*)d_in[4];
  const float* ls  = (const float*)d_in[5];
  const float* loc = (const float*)d_in[6];
  const float* gps = (const float*)d_in[7];
  float* out = (float*)d_out;
  float* ws  = (float*)d_ws;

  float*   h       = ws + OFF_H;
  float*   img     = ws + OFF_IMG;
  float*   img_n   = ws + OFF_IMGN;
  bf16_t*  img_bf  = (bf16_t*)(ws + OFF_IMGBF);
  float*   sumexp  = ws + OFF_STATS;
  unsigned* maxkey = (unsigned*)(ws + OFF_STATS + 1);
  unsigned* counter= (unsigned*)(ws + OFF_STATS + 2);
  int*     cidx    = (int*)(ws + OFF_CIDX);
  float*   cval    = ws + OFF_CVAL;

  // 1-2: MLP (f32 exact — keeps row-0 ranking reference-accurate via fixup path)
  mlp_gemm<DIN, DH, true><<<dim3(DH/32, N_IMG/32), 256, 0, stream>>>(
      img_feats, w1, b1, h, (unsigned*)(ws + OFF_STATS));
  mlp_gemm<DH, DOUT, false><<<dim3(DOUT/32, N_IMG/32), 256, 0, stream>>>(
      h, w2, b2, img, nullptr);
  // 3: normalize + bf16 cast
  norm_cast_kernel<<<N_IMG, 256, 0, stream>>>(img, img_n, img_bf);
  // 4: main logits GEMM (memory-bound; 98 m-groups * 16 = 1568 blocks)
  logits_kernel<<<1568, 256, 0, stream>>>(loc, img_bf, ls, out);
  // 5-8: row-0 softmax stats + exact top-5 fixup
  const int nb391 = (M_GAL + 255) / 256;
  row0_stats<<<nb391, 256, 0, stream>>>(out, sumexp, maxkey);
  collect_kernel<<<nb391, 256, 0, stream>>>(out, maxkey, counter, cidx);
  recompute_kernel<<<128, 256, 0, stream>>>(loc, img_n, ls, counter, cidx, cval);
  finalize_kernel<<<1, 256, 0, stream>>>(counter, cidx, cval, gps, sumexp, out);
}

// Round 2
// 481.319 us; speedup vs baseline: 1.0315x; 1.0315x over previous
//
#include <hip/hip_runtime.h>
#include <math.h>

#define N_IMG 256
#define DIN   768
#define DH    768
#define DOUT  512
#define M_GAL 100000
#define CAP   2048
#define MT    392   // padded count of 256-wide m-tiles (392*256 = 100352 >= 100000)

typedef __bf16 bf16_t;
typedef __bf16 bf16x8 __attribute__((ext_vector_type(8)));
typedef float  f32x4  __attribute__((ext_vector_type(4)));

// ---- workspace layout (float units) ----
#define OFF_H      0                               // 256*768
#define OFF_IMG    (N_IMG*DH)                      // 256*512 pre-norm
#define OFF_IMGN   (OFF_IMG  + N_IMG*DOUT)         // 256*512 f32 normalized
#define OFF_IMGT   (OFF_IMGN + N_IMG*DOUT)         // 256*512 bf16, [k/8][n][8] layout
#define OFF_STATS  (OFF_IMGT + N_IMG*DOUT/2)       // [0]=sumexp [1]=maxkey [2]=counter
#define OFF_CIDX   (OFF_STATS + 4)

#define OUT_GPS  ((size_t)N_IMG * (size_t)M_GAL)
#define OUT_PROB (OUT_GPS + 10)

__device__ inline unsigned fkey(float x) {
  unsigned u = __float_as_uint(x);
  return (u & 0x80000000u) ? ~u : (u | 0x80000000u);
}
__device__ inline float fkey_inv(unsigned k) {
  unsigned u = (k & 0x80000000u) ? (k ^ 0x80000000u) : ~k;
  return __uint_as_float(u);
}

// ---------------- MLP GEMM (f32 VALU, 32x32 tile, 2x2 micro) ----------------
// exact f32 path: keeps row-0 ranking reference-accurate via the f32 fixup
template<int KDIM, int NCOLS, bool RELU>
__global__ __launch_bounds__(256) void mlp_gemm(const float* __restrict__ A,
    const float* __restrict__ B, const float* __restrict__ bias,
    float* __restrict__ C, unsigned* stats_init) {
  if (stats_init && blockIdx.x == 0 && blockIdx.y == 0 && threadIdx.x == 0) {
    stats_init[0] = 0u; stats_init[1] = 0u; stats_init[2] = 0u;  // sumexp,maxkey,counter
  }
  __shared__ float As[32][34];
  __shared__ float Bs[32][34];
  const int t  = threadIdx.x;
  const int rowbase = blockIdx.y * 32;
  const int colbase = blockIdx.x * 32;
  const int sm = t >> 3;
  const int kc = (t & 7) << 2;
  const int ty = t >> 4, tx = t & 15;
  float a00 = 0.f, a01 = 0.f, a10 = 0.f, a11 = 0.f;
  for (int kt = 0; kt < KDIM; kt += 32) {
    float4 av = *(const float4*)(A + (size_t)(rowbase + sm) * KDIM + kt + kc);
    float4 bv = *(const float4*)(B + (size_t)(colbase + sm) * KDIM + kt + kc);
    __syncthreads();
    As[kc+0][sm] = av.x; As[kc+1][sm] = av.y; As[kc+2][sm] = av.z; As[kc+3][sm] = av.w;
    Bs[kc+0][sm] = bv.x; Bs[kc+1][sm] = bv.y; Bs[kc+2][sm] = bv.z; Bs[kc+3][sm] = bv.w;
    __syncthreads();
#pragma unroll
    for (int j = 0; j < 32; ++j) {
      float2 a = *(const float2*)(&As[j][2*ty]);
      float2 b = *(const float2*)(&Bs[j][2*tx]);
      a00 = fmaf(a.x, b.x, a00); a01 = fmaf(a.x, b.y, a01);
      a10 = fmaf(a.y, b.x, a10); a11 = fmaf(a.y, b.y, a11);
    }
  }
  const int r0 = rowbase + 2*ty;
  const int c0 = colbase + 2*tx;
  const float bb0 = bias[c0], bb1 = bias[c0+1];
  float v00 = a00 + bb0, v01 = a01 + bb1, v10 = a10 + bb0, v11 = a11 + bb1;
  if (RELU) {
    v00 = fmaxf(v00, 0.f); v01 = fmaxf(v01, 0.f);
    v10 = fmaxf(v10, 0.f); v11 = fmaxf(v11, 0.f);
  }
  C[(size_t)r0*NCOLS + c0]       = v00; C[(size_t)r0*NCOLS + c0 + 1]     = v01;
  C[(size_t)(r0+1)*NCOLS + c0]   = v10; C[(size_t)(r0+1)*NCOLS + c0 + 1] = v11;
}

// ---------------- normalize rows + bf16 cast into [k/8][n][8] layout ----------------
__global__ __launch_bounds__(256) void norm_cast_kernel(const float* __restrict__ img,
    float* __restrict__ img_n, bf16_t* __restrict__ img_t) {
  const int row = blockIdx.x, t = threadIdx.x;
  const float v0 = img[row*DOUT + t];
  const float v1 = img[row*DOUT + 256 + t];
  float s = v0*v0 + v1*v1;
  for (int o = 32; o > 0; o >>= 1) s += __shfl_down(s, o);
  __shared__ float ws4[4];
  if ((t & 63) == 0) ws4[t >> 6] = s;
  __syncthreads();
  const float tot = ws4[0] + ws4[1] + ws4[2] + ws4[3];
  const float inv = 1.0f / sqrtf(tot);
  const float n0 = v0 * inv, n1 = v1 * inv;
  img_n[row*DOUT + t]       = n0;
  img_n[row*DOUT + 256 + t] = n1;
  // transposed bf16 layout: element (n, k) -> img_t[((k>>3)*N_IMG + n)*8 + (k&7)]
  const int k0 = t, k1 = t + 256;
  img_t[(((k0 >> 3)*N_IMG) + row)*8 + (k0 & 7)] = (bf16_t)n0;
  img_t[(((k1 >> 3)*N_IMG) + row)*8 + (k1 & 7)] = (bf16_t)n1;
}

// ---------------- main logits GEMM: barrier-free streaming K-loop ----------------
// Block: n-tile 64 images (A slab 64 KB LDS, staged once), m-tile 256 gallery rows
// (one 64-row sub-tile per wave). B fragments load f32 straight from `loc` into
// registers in MFMA layout, cvt to bf16 in-reg. No __syncthreads in the K-loop.
__global__ __launch_bounds__(256) void logits_kernel(const float* __restrict__ loc,
    const bf16_t* __restrict__ img_t, const float* __restrict__ ls,
    float* __restrict__ out, float* __restrict__ sumexp, unsigned* __restrict__ maxkey) {
  __shared__ bf16_t Asl[64 * 64 * 8];   // [kb 0..63][row 0..63][8] : 64 KB
  const int t = threadIdx.x;
  const int w = t >> 6, l = t & 63;
  const int bx = blockIdx.x;
  // swizzle: same m-tile's 4 n-tiles are 8 blocks apart (same XCD round-robin)
  const int mtile = (bx & 7) + (bx >> 5) * 8;
  const int ntile = (bx >> 3) & 3;
  const int mb = mtile * 256;
  const int nb = ntile * 64;

  // ---- stage A slab once: 64 chunks of 1 KB, perfectly coalesced, 16 B/lane ----
#pragma unroll
  for (int r = 0; r < 16; ++r) {
    const int c = r * 4 + w;   // kb index
    __builtin_amdgcn_global_load_lds(
        (__attribute__((address_space(1))) void*)(img_t + ((size_t)c * N_IMG + nb + l) * 8),
        (__attribute__((address_space(3))) void*)(Asl + (c * 64 + l) * 8),
        16, 0, 0);
  }
  __syncthreads();   // one-time drain; K-loop below is barrier-free

  const int lr = l & 15, lq = l >> 4;
  const int mw = mb + w * 64;            // wave's gallery sub-tile base
  f32x4 acc[4][4];
#pragma unroll
  for (int i = 0; i < 4; ++i)
#pragma unroll
    for (int j = 0; j < 4; ++j)
      acc[i][j] = (f32x4){0.f, 0.f, 0.f, 0.f};

  // B fragment row per j (clamped; stores guarded later)
  int mrow[4];
#pragma unroll
  for (int j = 0; j < 4; ++j) {
    int m = mw + j * 16 + lr;
    mrow[j] = m < M_GAL ? m : (M_GAL - 1);
  }

#pragma unroll 2
  for (int kt = 0; kt < 16; ++kt) {
    // ---- B: 8 independent float4 streaming loads (128-B coalesced groups) ----
    float4 b0[4], b1[4];
#pragma unroll
    for (int j = 0; j < 4; ++j) {
      const float* p = loc + (size_t)mrow[j] * 512 + kt * 32 + lq * 8;
      b0[j] = *(const float4*)p;
      b1[j] = *(const float4*)(p + 4);
    }
    // ---- A fragments: conflict-free ds_read_b128 (lr lanes contiguous) ----
    bf16x8 af[4];
#pragma unroll
    for (int i = 0; i < 4; ++i)
      af[i] = *(const bf16x8*)(Asl + ((kt * 4 + lq) * 64 + i * 16 + lr) * 8);
    // ---- cvt + MFMA ----
#pragma unroll
    for (int j = 0; j < 4; ++j) {
      bf16x8 bfr;
      bfr[0] = (bf16_t)b0[j].x; bfr[1] = (bf16_t)b0[j].y;
      bfr[2] = (bf16_t)b0[j].z; bfr[3] = (bf16_t)b0[j].w;
      bfr[4] = (bf16_t)b1[j].x; bfr[5] = (bf16_t)b1[j].y;
      bfr[6] = (bf16_t)b1[j].z; bfr[7] = (bf16_t)b1[j].w;
#pragma unroll
      for (int i = 0; i < 4; ++i)
        acc[i][j] = __builtin_amdgcn_mfma_f32_16x16x32_bf16(af[i], bfr, acc[i][j], 0, 0, 0);
    }
  }

  const float scale = expf(ls[0]);
  // ---- fold row-0 softmax stats into epilogue (image row 0 lives in ntile 0) ----
  if (ntile == 0) {
    float mx = -1e30f, se = 0.f;
    if (lq == 0) {           // image row = 0*16 + 0*4 + reg0 -> lq==0, i==0, reg==0
#pragma unroll
      for (int j = 0; j < 4; ++j) {
        const int m = mw + j * 16 + lr;
        if (m < M_GAL) {
          const float v = scale * acc[0][j][0];
          mx = fmaxf(mx, v);
          se += expf(v);
        }
      }
    }
#pragma unroll
    for (int o = 1; o < 64; o <<= 1) {
      mx = fmaxf(mx, __shfl_xor(mx, o));
      se += __shfl_xor(se, o);
    }
    if (l == 0) { atomicAdd(sumexp, se); atomicMax(maxkey, fkey(mx)); }
  }
  // ---- store: D row = image = lq*4 + reg (+i*16), col = gallery = lr (+j*16) ----
#pragma unroll
  for (int i = 0; i < 4; ++i) {
    const int imgr = nb + i * 16 + lq * 4;
#pragma unroll
    for (int j = 0; j < 4; ++j) {
      const int gal = mw + j * 16 + lr;
      if (gal < M_GAL) {
        const size_t base = (size_t)imgr * M_GAL + gal;
#pragma unroll
        for (int r = 0; r < 4; ++r)
          out[base + (size_t)r * M_GAL] = scale * acc[i][j][r];
      }
    }
  }
}

// ---------------- collect candidates within 0.8 of row-0 max ----------------
__global__ __launch_bounds__(256) void collect_kernel(const float* __restrict__ out,
    const unsigned* __restrict__ maxkey, unsigned* __restrict__ counter,
    int* __restrict__ cidx) {
  const int i = blockIdx.x * 256 + threadIdx.x;
  if (i >= M_GAL) return;
  const float thresh = fkey_inv(*maxkey) - 0.8f;
  if (out[i] > thresh) {
    const unsigned p = atomicAdd(counter, 1u);
    if (p < CAP) cidx[p] = i;
  }
}

// ---------------- fused exact f32 recompute + top-5 + outputs ----------------
__global__ __launch_bounds__(256) void final_kernel(const float* __restrict__ loc,
    const float* __restrict__ img_n, const float* __restrict__ ls,
    const unsigned* __restrict__ counter, const int* __restrict__ cidx,
    const float* __restrict__ gps, const float* __restrict__ sumexp,
    float* __restrict__ out) {
  __shared__ float v[CAP];
  __shared__ int   id[CAP];
  __shared__ float rv[256];
  __shared__ int   ri[256];
  __shared__ int   rs[256];
  __shared__ float a0[DOUT];
  const int t = threadIdx.x;
  const unsigned cnt = *counter;
  const int n = (int)(cnt < CAP ? cnt : CAP);
  const float scale = expf(ls[0]);
  a0[t] = img_n[t]; a0[t + 256] = img_n[t + 256];
  __syncthreads();
  for (int c = t; c < CAP; c += 256) {
    if (c < n) {
      const int gi = cidx[c];
      const float* B = loc + (size_t)gi * 512;
      float s = 0.f;
#pragma unroll 8
      for (int k = 0; k < 512; k += 4) {
        const float4 b = *(const float4*)(B + k);
        s = fmaf(a0[k], b.x, s); s = fmaf(a0[k+1], b.y, s);
        s = fmaf(a0[k+2], b.z, s); s = fmaf(a0[k+3], b.w, s);
      }
      v[c] = scale * s; id[c] = gi;
    } else { v[c] = -1e30f; id[c] = 0x7fffffff; }
  }
  const float se = *sumexp;
  __syncthreads();
  for (int k = 0; k < 5; ++k) {
    float bv = -1e30f; int bidx = 0x7fffffff; int bslot = -1;
    for (int i = t; i < CAP; i += 256) {
      const float vi = v[i]; const int ii = id[i];
      if (vi > bv || (vi == bv && ii < bidx)) { bv = vi; bidx = ii; bslot = i; }
    }
    rv[t] = bv; ri[t] = bidx; rs[t] = bslot;
    __syncthreads();
    for (int s = 128; s > 0; s >>= 1) {
      if (t < s) {
        if (rv[t+s] > rv[t] || (rv[t+s] == rv[t] && ri[t+s] < ri[t])) {
          rv[t] = rv[t+s]; ri[t] = ri[t+s]; rs[t] = rs[t+s];
        }
      }
      __syncthreads();
    }
    if (t == 0) {
      const int sl = rs[0]; const int gi = ri[0]; const float lv = rv[0];
      float g0 = 0.f, g1 = 0.f, pr = 0.f;
      if (sl >= 0 && gi != 0x7fffffff) {
        g0 = gps[(size_t)gi*2]; g1 = gps[(size_t)gi*2 + 1];
        pr = expf(lv) / se;
        v[sl] = -1e30f; id[sl] = 0x7fffffff;
      }
      out[OUT_GPS + 2*k]     = g0;
      out[OUT_GPS + 2*k + 1] = g1;
      out[OUT_PROB + k]      = pr;
    }
    __syncthreads();
  }
}

extern "C" void kernel_launch(void* const* d_in, const int* in_sizes, int n_in,
                              void* d_out, int out_size, void* d_ws, size_t ws_size,
                              hipStream_t stream) {
  const float* img_feats = (const float*)d_in[0];
  const float* w1  = (const float*)d_in[1];
  const float* b1  = (const float*)d_in[2];
  const float* w2  = (const float*)d_in[3];
  const float* b2  = (const float*)d_in[4];
  const float* ls  = (const float*)d_in[5];
  const float* loc = (const float*)d_in[6];
  const float* gps = (const float*)d_in[7];
  float* out = (float*)d_out;
  float* ws  = (float*)d_ws;

  float*    h       = ws + OFF_H;
  float*    img     = ws + OFF_IMG;
  float*    img_n   = ws + OFF_IMGN;
  bf16_t*   img_t   = (bf16_t*)(ws + OFF_IMGT);
  float*    sumexp  = ws + OFF_STATS;
  unsigned* maxkey  = (unsigned*)(ws + OFF_STATS + 1);
  unsigned* counter = (unsigned*)(ws + OFF_STATS + 2);
  int*      cidx    = (int*)(ws + OFF_CIDX);

  // 1-2: MLP head (f32 exact); first launch also zeroes the stats words
  mlp_gemm<DIN, DH, true><<<dim3(DH/32, N_IMG/32), 256, 0, stream>>>(
      img_feats, w1, b1, h, (unsigned*)(ws + OFF_STATS));
  mlp_gemm<DH, DOUT, false><<<dim3(DOUT/32, N_IMG/32), 256, 0, stream>>>(
      h, w2, b2, img, nullptr);
  // 3: normalize + bf16 transpose-cast
  norm_cast_kernel<<<N_IMG, 256, 0, stream>>>(img, img_n, img_t);
  // 4: streaming logits GEMM (+ row-0 stats folded into epilogue)
  logits_kernel<<<MT * 4, 256, 0, stream>>>(loc, img_t, ls, out, sumexp, maxkey);
  // 5: candidate collection
  collect_kernel<<<(M_GAL + 255) / 256, 256, 0, stream>>>(out, maxkey, counter, cidx);
  // 6: exact f32 recompute + top-5 + gps/prob outputs
  final_kernel<<<1, 256, 0, stream>>>(loc, img_n, ls, counter, cidx, gps, sumexp, out);
}

// Round 3
// 474.630 us; speedup vs baseline: 1.0460x; 1.0141x over previous
//
#include <hip/hip_runtime.h>
#include <math.h>

#define N_IMG 256
#define DIN   768
#define DH    768
#define DOUT  512
#define M_GAL 100000
#define CAP   2048
#define MT    784   // m-tiles of 128 gallery rows (784*128 = 100352 >= 100000)

typedef __bf16 bf16_t;
typedef __bf16 bf16x8 __attribute__((ext_vector_type(8)));
typedef float  f32x4  __attribute__((ext_vector_type(4)));

// ---- workspace layout (float units) ----
#define OFF_H      0                               // 256*768
#define OFF_IMG    (N_IMG*DH)                      // 256*512 pre-norm
#define OFF_IMGN   (OFF_IMG  + N_IMG*DOUT)         // 256*512 f32 normalized
#define OFF_IMGT   (OFF_IMGN + N_IMG*DOUT)         // 256*512 bf16, [k/8][n][8] layout
#define OFF_STATS  (OFF_IMGT + N_IMG*DOUT/2)       // [0]=sumexp [1]=maxkey [2]=counter
#define OFF_CIDX   (OFF_STATS + 4)
#define OFF_CVAL   (OFF_CIDX + CAP)

#define OUT_GPS  ((size_t)N_IMG * (size_t)M_GAL)
#define OUT_PROB (OUT_GPS + 10)

__device__ inline unsigned fkey(float x) {
  unsigned u = __float_as_uint(x);
  return (u & 0x80000000u) ? ~u : (u | 0x80000000u);
}
__device__ inline float fkey_inv(unsigned k) {
  unsigned u = (k & 0x80000000u) ? (k ^ 0x80000000u) : ~k;
  return __uint_as_float(u);
}

// ---------------- MLP GEMM (f32 VALU, 32x32 tile, 2x2 micro) ----------------
// exact f32 path: keeps row-0 ranking reference-accurate via the f32 fixup
template<int KDIM, int NCOLS, bool RELU>
__global__ __launch_bounds__(256) void mlp_gemm(const float* __restrict__ A,
    const float* __restrict__ B, const float* __restrict__ bias,
    float* __restrict__ C, unsigned* stats_init) {
  if (stats_init && blockIdx.x == 0 && blockIdx.y == 0 && threadIdx.x == 0) {
    stats_init[0] = 0u; stats_init[1] = 0u; stats_init[2] = 0u;  // sumexp,maxkey,counter
  }
  __shared__ float As[32][34];
  __shared__ float Bs[32][34];
  const int t  = threadIdx.x;
  const int rowbase = blockIdx.y * 32;
  const int colbase = blockIdx.x * 32;
  const int sm = t >> 3;
  const int kc = (t & 7) << 2;
  const int ty = t >> 4, tx = t & 15;
  float a00 = 0.f, a01 = 0.f, a10 = 0.f, a11 = 0.f;
  for (int kt = 0; kt < KDIM; kt += 32) {
    float4 av = *(const float4*)(A + (size_t)(rowbase + sm) * KDIM + kt + kc);
    float4 bv = *(const float4*)(B + (size_t)(colbase + sm) * KDIM + kt + kc);
    __syncthreads();
    As[kc+0][sm] = av.x; As[kc+1][sm] = av.y; As[kc+2][sm] = av.z; As[kc+3][sm] = av.w;
    Bs[kc+0][sm] = bv.x; Bs[kc+1][sm] = bv.y; Bs[kc+2][sm] = bv.z; Bs[kc+3][sm] = bv.w;
    __syncthreads();
#pragma unroll
    for (int j = 0; j < 32; ++j) {
      float2 a = *(const float2*)(&As[j][2*ty]);
      float2 b = *(const float2*)(&Bs[j][2*tx]);
      a00 = fmaf(a.x, b.x, a00); a01 = fmaf(a.x, b.y, a01);
      a10 = fmaf(a.y, b.x, a10); a11 = fmaf(a.y, b.y, a11);
    }
  }
  const int r0 = rowbase + 2*ty;
  const int c0 = colbase + 2*tx;
  const float bb0 = bias[c0], bb1 = bias[c0+1];
  float v00 = a00 + bb0, v01 = a01 + bb1, v10 = a10 + bb0, v11 = a11 + bb1;
  if (RELU) {
    v00 = fmaxf(v00, 0.f); v01 = fmaxf(v01, 0.f);
    v10 = fmaxf(v10, 0.f); v11 = fmaxf(v11, 0.f);
  }
  C[(size_t)r0*NCOLS + c0]       = v00; C[(size_t)r0*NCOLS + c0 + 1]     = v01;
  C[(size_t)(r0+1)*NCOLS + c0]   = v10; C[(size_t)(r0+1)*NCOLS + c0 + 1] = v11;
}

// ---------------- normalize rows + bf16 cast into [k/8][n][8] layout ----------------
__global__ __launch_bounds__(256) void norm_cast_kernel(const float* __restrict__ img,
    float* __restrict__ img_n, bf16_t* __restrict__ img_t) {
  const int row = blockIdx.x, t = threadIdx.x;
  const float v0 = img[row*DOUT + t];
  const float v1 = img[row*DOUT + 256 + t];
  float s = v0*v0 + v1*v1;
  for (int o = 32; o > 0; o >>= 1) s += __shfl_down(s, o);
  __shared__ float ws4[4];
  if ((t & 63) == 0) ws4[t >> 6] = s;
  __syncthreads();
  const float tot = ws4[0] + ws4[1] + ws4[2] + ws4[3];
  const float inv = 1.0f / sqrtf(tot);
  const float n0 = v0 * inv, n1 = v1 * inv;
  img_n[row*DOUT + t]       = n0;
  img_n[row*DOUT + 256 + t] = n1;
  // transposed bf16 layout: element (n, k) -> img_t[((k>>3)*N_IMG + n)*8 + (k&7)]
  const int k0 = t, k1 = t + 256;
  img_t[(((k0 >> 3)*N_IMG) + row)*8 + (k0 & 7)] = (bf16_t)n0;
  img_t[(((k1 >> 3)*N_IMG) + row)*8 + (k1 & 7)] = (bf16_t)n1;
}

// ---------------- main logits GEMM ----------------
// Block: 64 images (A slab: K staged in two 32 KB halves) x 128 gallery rows.
// Wave: 64 img x 32 gal (acc = 32 VGPRs). B streamed f32 from `loc` into regs
// with explicit depth-2 rotating prefetch; no barriers in the K-loop.
// __launch_bounds__(256,4): 4 waves/SIMD -> 16 waves/CU with 32 KB LDS.
__global__ __launch_bounds__(256, 4) void logits_kernel(const float* __restrict__ loc,
    const bf16_t* __restrict__ img_t, const float* __restrict__ ls,
    float* __restrict__ out, float* __restrict__ sumexp, unsigned* __restrict__ maxkey) {
  __shared__ bf16_t Asl[32 * 64 * 8];   // 32 KB: [kb 0..31][row 0..63][8]
  const int t = threadIdx.x;
  const int w = t >> 6, l = t & 63;
  const int bx = blockIdx.x;
  // swizzle: same m-tile's 4 n-tiles are 8 blocks apart (same XCD round-robin)
  const int mtile = (bx & 7) + (bx >> 5) * 8;   // 0..783
  const int ntile = (bx >> 3) & 3;
  const int mb = mtile * 128;
  const int nb = ntile * 64;
  const int lr = l & 15, lq = l >> 4;
  const int mw = mb + w * 32;            // wave's 32-row gallery sub-tile

  // B row pointers (clamped; stores guarded by true index later)
  const float* bp[2];
#pragma unroll
  for (int j = 0; j < 2; ++j) {
    int m = mw + j * 16 + lr;
    m = m < M_GAL ? m : (M_GAL - 1);
    bp[j] = loc + (size_t)m * 512 + lq * 8;
  }

  f32x4 acc[4][2];
#pragma unroll
  for (int i = 0; i < 4; ++i)
#pragma unroll
    for (int j = 0; j < 2; ++j)
      acc[i][j] = (f32x4){0.f, 0.f, 0.f, 0.f};

  float4 B0[3][2], B1[3][2];   // rotating depth-2 prefetch slots

#define ISSUE(kt) {                                                  \
    const int s_ = (kt) % 3;                                         \
    _Pragma("unroll")                                                \
    for (int j_ = 0; j_ < 2; ++j_) {                                 \
      const float* p_ = bp[j_] + (kt) * 32;                          \
      B0[s_][j_] = *(const float4*)p_;                               \
      B1[s_][j_] = *(const float4*)(p_ + 4);                         \
    } }

#define COMPUTE(kt) {                                                \
    const int kb_ = ((kt) & 7) * 4 + lq;                             \
    const int s_  = (kt) % 3;                                        \
    bf16x8 af_[4];                                                   \
    _Pragma("unroll")                                                \
    for (int i_ = 0; i_ < 4; ++i_)                                   \
      af_[i_] = *(const bf16x8*)(Asl + (kb_ * 64 + i_ * 16 + lr) * 8); \
    _Pragma("unroll")                                                \
    for (int j_ = 0; j_ < 2; ++j_) {                                 \
      bf16x8 bf_;                                                    \
      bf_[0] = (bf16_t)B0[s_][j_].x; bf_[1] = (bf16_t)B0[s_][j_].y;  \
      bf_[2] = (bf16_t)B0[s_][j_].z; bf_[3] = (bf16_t)B0[s_][j_].w;  \
      bf_[4] = (bf16_t)B1[s_][j_].x; bf_[5] = (bf16_t)B1[s_][j_].y;  \
      bf_[6] = (bf16_t)B1[s_][j_].z; bf_[7] = (bf16_t)B1[s_][j_].w;  \
      _Pragma("unroll")                                              \
      for (int i_ = 0; i_ < 4; ++i_)                                 \
        acc[i_][j_] = __builtin_amdgcn_mfma_f32_16x16x32_bf16(af_[i_], bf_, acc[i_][j_], 0, 0, 0); \
    } }

  // ---- issue first B prefetches, then stage A half 0 (K 0..255, 32 KB) ----
  ISSUE(0); ISSUE(1);
#pragma unroll
  for (int r = 0; r < 8; ++r) {
    const int c = r * 4 + w;   // kb 0..31
    __builtin_amdgcn_global_load_lds(
        (__attribute__((address_space(1))) void*)(img_t + ((size_t)c * N_IMG + nb + l) * 8),
        (__attribute__((address_space(3))) void*)(Asl + (c * 64 + l) * 8),
        16, 0, 0);
  }
  __syncthreads();   // drain A half 0 (B prefetch arrives with it)

#pragma unroll
  for (int kt = 0; kt < 8; ++kt) {
    ISSUE(kt + 2);
    COMPUTE(kt);
  }

  // ---- restage A half 1 (K 256..511) ----
  __syncthreads();   // all waves done reading half 0
#pragma unroll
  for (int r = 0; r < 8; ++r) {
    const int c = r * 4 + w;
    __builtin_amdgcn_global_load_lds(
        (__attribute__((address_space(1))) void*)(img_t + ((size_t)(32 + c) * N_IMG + nb + l) * 8),
        (__attribute__((address_space(3))) void*)(Asl + (c * 64 + l) * 8),
        16, 0, 0);
  }
  __syncthreads();   // drain A half 1

#pragma unroll
  for (int kt = 8; kt < 16; ++kt) {
    if (kt < 14) { ISSUE(kt + 2); }
    COMPUTE(kt);
  }
#undef ISSUE
#undef COMPUTE

  const float scale = expf(ls[0]);
  // ---- row-0 softmax stats folded into epilogue (image 0 is in ntile 0) ----
  if (ntile == 0) {
    float mx = -1e30f, se = 0.f;
    if (lq == 0) {     // image row 0 = i=0, lq=0, reg 0
#pragma unroll
      for (int j = 0; j < 2; ++j) {
        const int m = mw + j * 16 + lr;
        if (m < M_GAL) {
          const float v = scale * acc[0][j][0];
          mx = fmaxf(mx, v);
          se += expf(v);
        }
      }
    }
#pragma unroll
    for (int o = 1; o < 64; o <<= 1) {
      mx = fmaxf(mx, __shfl_xor(mx, o));
      se += __shfl_xor(se, o);
    }
    if (l == 0) { atomicAdd(sumexp, se); atomicMax(maxkey, fkey(mx)); }
  }
  // ---- store: D row = image = lq*4 + reg (+i*16), col = gallery = lr (+j*16) ----
#pragma unroll
  for (int i = 0; i < 4; ++i) {
    const int imgr = nb + i * 16 + lq * 4;
#pragma unroll
    for (int j = 0; j < 2; ++j) {
      const int gal = mw + j * 16 + lr;
      if (gal < M_GAL) {
        const size_t base = (size_t)imgr * M_GAL + gal;
#pragma unroll
        for (int r = 0; r < 4; ++r)
          out[base + (size_t)r * M_GAL] = scale * acc[i][j][r];
      }
    }
  }
}

// ---------------- collect candidates within 0.8 of row-0 max ----------------
__global__ __launch_bounds__(256) void collect_kernel(const float* __restrict__ out,
    const unsigned* __restrict__ maxkey, unsigned* __restrict__ counter,
    int* __restrict__ cidx) {
  const int i = blockIdx.x * 256 + threadIdx.x;
  if (i >= M_GAL) return;
  const float thresh = fkey_inv(*maxkey) - 0.8f;
  if (out[i] > thresh) {
    const unsigned p = atomicAdd(counter, 1u);
    if (p < CAP) cidx[p] = i;
  }
}

// ---------------- exact f32 recompute of candidate logits (multi-block) ----------------
__global__ __launch_bounds__(256) void recompute_kernel(const float* __restrict__ loc,
    const float* __restrict__ img_n, const float* __restrict__ ls,
    const unsigned* __restrict__ counter, const int* __restrict__ cidx,
    float* __restrict__ cval) {
  const int w = threadIdx.x >> 6, l = threadIdx.x & 63;
  const unsigned cnt = *counter;
  const int n = (int)(cnt < CAP ? cnt : CAP);
  const float scale = expf(ls[0]);
  for (int c = blockIdx.x * 4 + w; c < n; c += gridDim.x * 4) {
    const int idx = cidx[c];
    const float* B = loc + (size_t)idx * 512;
    float s = 0.f;
#pragma unroll
    for (int e = 0; e < 8; ++e) s = fmaf(img_n[l + e*64], B[l + e*64], s);
    for (int o = 32; o > 0; o >>= 1) s += __shfl_down(s, o);
    if (l == 0) cval[c] = scale * s;
  }
}

// ---------------- exact top-5 among candidates + outputs ----------------
__global__ __launch_bounds__(256) void finalize_kernel(const unsigned* __restrict__ counter,
    const int* __restrict__ cidx, const float* __restrict__ cval,
    const float* __restrict__ gps, const float* __restrict__ sumexp,
    float* __restrict__ out) {
  __shared__ float v[CAP];
  __shared__ int   id[CAP];
  __shared__ float rv[256];
  __shared__ int   ri[256];
  __shared__ int   rs[256];
  const int t = threadIdx.x;
  const unsigned cnt = *counter;
  const int n = (int)(cnt < CAP ? cnt : CAP);
  for (int i = t; i < CAP; i += 256) {
    v[i]  = (i < n) ? cval[i] : -1e30f;
    id[i] = (i < n) ? cidx[i] : 0x7fffffff;
  }
  const float se = *sumexp;
  __syncthreads();
  for (int k = 0; k < 5; ++k) {
    float bv = -1e30f; int bidx = 0x7fffffff; int bslot = -1;
    for (int i = t; i < CAP; i += 256) {
      const float vi = v[i]; const int ii = id[i];
      if (vi > bv || (vi == bv && ii < bidx)) { bv = vi; bidx = ii; bslot = i; }
    }
    rv[t] = bv; ri[t] = bidx; rs[t] = bslot;
    __syncthreads();
    for (int s = 128; s > 0; s >>= 1) {
      if (t < s) {
        if (rv[t+s] > rv[t] || (rv[t+s] == rv[t] && ri[t+s] < ri[t])) {
          rv[t] = rv[t+s]; ri[t] = ri[t+s]; rs[t] = rs[t+s];
        }
      }
      __syncthreads();
    }
    if (t == 0) {
      const int sl = rs[0]; const int gi = ri[0]; const float lv = rv[0];
      float g0 = 0.f, g1 = 0.f, pr = 0.f;
      if (sl >= 0 && gi != 0x7fffffff) {
        g0 = gps[(size_t)gi*2]; g1 = gps[(size_t)gi*2 + 1];
        pr = expf(lv) / se;
        v[sl] = -1e30f; id[sl] = 0x7fffffff;
      }
      out[OUT_GPS + 2*k]     = g0;
      out[OUT_GPS + 2*k + 1] = g1;
      out[OUT_PROB + k]      = pr;
    }
    __syncthreads();
  }
}

extern "C" void kernel_launch(void* const* d_in, const int* in_sizes, int n_in,
                              void* d_out, int out_size, void* d_ws, size_t ws_size,
                              hipStream_t stream) {
  const float* img_feats = (const float*)d_in[0];
  const float* w1  = (const float*)d_in[1];
  const float* b1  = (const float*)d_in[2];
  const float* w2  = (const float*)d_in[3];
  const float* b2  = (const float*)d_in[4];
  const float* ls  = (const float*)d_in[5];
  const float* loc = (const float*)d_in[6];
  const float* gps = (const float*)d_in[7];
  float* out = (float*)d_out;
  float* ws  = (float*)d_ws;

  float*    h       = ws + OFF_H;
  float*    img     = ws + OFF_IMG;
  float*    img_n   = ws + OFF_IMGN;
  bf16_t*   img_t   = (bf16_t*)(ws + OFF_IMGT);
  float*    sumexp  = ws + OFF_STATS;
  unsigned* maxkey  = (unsigned*)(ws + OFF_STATS + 1);
  unsigned* counter = (unsigned*)(ws + OFF_STATS + 2);
  int*      cidx    = (int*)(ws + OFF_CIDX);
  float*    cval    = ws + OFF_CVAL;

  // 1-2: MLP head (f32 exact); first launch also zeroes the stats words
  mlp_gemm<DIN, DH, true><<<dim3(DH/32, N_IMG/32), 256, 0, stream>>>(
      img_feats, w1, b1, h, (unsigned*)(ws + OFF_STATS));
  mlp_gemm<DH, DOUT, false><<<dim3(DOUT/32, N_IMG/32), 256, 0, stream>>>(
      h, w2, b2, img, nullptr);
  // 3: normalize + bf16 transpose-cast
  norm_cast_kernel<<<N_IMG, 256, 0, stream>>>(img, img_n, img_t);
  // 4: streaming logits GEMM (+ row-0 stats folded into epilogue)
  logits_kernel<<<MT * 4, 256, 0, stream>>>(loc, img_t, ls, out, sumexp, maxkey);
  // 5: candidate collection (row 0 only: 400 KB)
  collect_kernel<<<(M_GAL + 255) / 256, 256, 0, stream>>>(out, maxkey, counter, cidx);
  // 6-7: exact f32 recompute (multi-block) + top-5 + gps/prob outputs
  recompute_kernel<<<128, 256, 0, stream>>>(loc, img_n, ls, counter, cidx, cval);
  finalize_kernel<<<1, 256, 0, stream>>>(counter, cidx, cval, gps, sumexp, out);
}